// Round 12
// baseline (1171.095 us; speedup 1.0000x reference)
//
#include <hip/hip_runtime.h>
#include <hip/hip_fp16.h>

// Sinkhorn OT: n=m=4096, d=32, reg=0.1, 100 iterations, uniform marginals.
// R17 = R15 core REVERTED (R16's 1-wave/row regressed: 48% occupancy, same
// exchange-bound critical path) + two protocol cuts:
//  (1) u64 mailbox polling across all 1024 threads (2 u64/thread, was 8
//      u32 over 512): phase check is one masked 64-bit compare; halves the
//      poll-load storm (FETCH showed ~180 re-reads/line/half-pass) and
//      shortens the per-half-pass tail.
//  (2) epilogue FUSED into the persist kernel: at loop exit each block
//      publishes its 8 final fp32 v into mbv32 (self-validating: v>0 so
//      sign bit 0 = valid; sentinel 0xFFFFFFFF and 0xAA poison have sign
//      set), polls all 4096 into LDS, and computes its own 8 output rows
//      with the exact old-epilogue arithmetic (bit-identical). Removes a
//      dispatch boundary and absorbs straggler jitter under ~30us of
//      independent per-block work. Final u is block-local (registers).
// Main loop numerics bit-identical to R11..R16 (same operand values, same
// dot2/reduce/divide order). Freeze (v(t)==v(t-2), phase bit15) unchanged.
// 512 blocks x 1024 thr plain launch: 8192 waves = device capacity,
// co-residency by occupancy arithmetic (proved by R15).

#define NN 4096
#define MM 4096
#define DD 32
#define N_ITERS 100

static constexpr float INV_REG = 10.0f;
static constexpr float A_MARG  = 1.0f / 4096.0f;
static constexpr float B_MARG  = 1.0f / 4096.0f;

typedef _Float16 h2_t __attribute__((ext_vector_type(2)));

static __device__ __forceinline__ float dot2(unsigned a, unsigned b, float acc) {
#if __has_builtin(__builtin_amdgcn_fdot2)
    return __builtin_amdgcn_fdot2(__builtin_bit_cast(h2_t, a),
                                  __builtin_bit_cast(h2_t, b), acc, false);
#else
    float2 fa = __half22float2(*(const __half2*)&a);
    float2 fb = __half22float2(*(const __half2*)&b);
    acc = fmaf(fa.x, fb.x, acc);
    return fmaf(fa.y, fb.y, acc);
#endif
}

static __device__ __forceinline__ unsigned ld_dev_u32(const unsigned* p) {
    return __hip_atomic_load(p, __ATOMIC_RELAXED, __HIP_MEMORY_SCOPE_AGENT);
}
static __device__ __forceinline__ void st_dev_u32(unsigned* p, unsigned v) {
    __hip_atomic_store(p, v, __ATOMIC_RELAXED, __HIP_MEMORY_SCOPE_AGENT);
}
static __device__ __forceinline__ unsigned long long ld_dev_u64(const unsigned long long* p) {
    return __hip_atomic_load(p, __ATOMIC_RELAXED, __HIP_MEMORY_SCOPE_AGENT);
}

// ---------------------------------------------------------------------------
// One fused K-build dispatch. z=0: Kh[i][j]=exp(-||x_i-y_j||^2/reg) from
// (p=x, q=y); z=1: KTh from (p=y, q=x). z==0,by==0 also inits mailboxes:
// mbu/mbv phase 0 (invalid), mbv32 sentinel 0xFFFFFFFF (sign set = invalid).
// grid: (16, 256, 2), block 256
// ---------------------------------------------------------------------------
__global__ void compute_K_half(const float* __restrict__ x, const float* __restrict__ y,
                               __half* __restrict__ Kh, __half* __restrict__ KTh,
                               unsigned* __restrict__ mbu, unsigned* __restrict__ mbv,
                               unsigned* __restrict__ mbv32) {
    const int tid = threadIdx.x;
    const int j   = blockIdx.x * 256 + tid;
    const int r0  = blockIdx.y * 16;
    const int z   = blockIdx.z;
    const float* __restrict__ p = z ? y : x;
    const float* __restrict__ q = z ? x : y;
    __half* __restrict__ dst    = z ? KTh : Kh;

    if (z == 0 && blockIdx.y == 0) {
        mbu[j]   = 0u;
        mbv[j]   = 0u;
        mbv32[j] = 0xFFFFFFFFu;
    }

    float qv[DD];
    const float4* q4 = (const float4*)(q + (size_t)j * DD);
#pragma unroll
    for (int k = 0; k < DD / 4; ++k) {
        float4 t = q4[k];
        qv[4 * k + 0] = t.x; qv[4 * k + 1] = t.y;
        qv[4 * k + 2] = t.z; qv[4 * k + 3] = t.w;
    }

    __shared__ float ps[16 * DD];
    ps[tid]       = p[(size_t)r0 * DD + tid];
    ps[tid + 256] = p[(size_t)r0 * DD + tid + 256];
    __syncthreads();

#pragma unroll 4
    for (int ii = 0; ii < 16; ++ii) {
        float acc = 0.0f;
#pragma unroll
        for (int k = 0; k < DD; ++k) {
            float d = ps[ii * DD + k] - qv[k];
            acc = fmaf(d, d, acc);
        }
        dst[(size_t)(r0 + ii) * MM + j] = __float2half(__expf(-acc * INV_REG));
    }
}

// ---------------------------------------------------------------------------
// Persistent kernel: 100 iterations + fused epilogue. 512 blocks x 1024 thr
// (16 waves), 2 waves per row, 4 fdot2 chains, matrix register-resident,
// fused val|phase row mailboxes with u64 polling.
// ---------------------------------------------------------------------------
__global__ void __launch_bounds__(1024, 8)
sinkhorn_all(const float* __restrict__ x, const float* __restrict__ y,
             const __half* __restrict__ Kh, const __half* __restrict__ KTh,
             float* __restrict__ out,
             unsigned* __restrict__ mbu, unsigned* __restrict__ mbv,
             unsigned* __restrict__ mbv32) {
    __shared__ __align__(16) __half vlds[MM];   // 8 KB operand buffer
    __shared__ float vfin[MM];                  // 16 KB final fp32 v
    __shared__ float xs[8 * DD];                // block's 8 x-rows
    __shared__ float ufin[8];                   // block's 8 final u
    __shared__ float part[16];
    __shared__ unsigned fb_lds[16];
    const int tid  = threadIdx.x;
    const int lane = tid & 63;
    const int w    = tid >> 6;          // wave 0..15
    const int rib  = w >> 1;            // row-in-block 0..7
    const int hlf  = w & 1;             // half-row
    const int bid  = blockIdx.x;
    const int i    = bid * 8 + rib;
    const int g0   = hlf * 256 + lane;  // uint4 index into 512-uint4 row
    const uint4* __restrict__ MU = (const uint4*)(Kh  + (size_t)i * MM);
    const uint4* __restrict__ MV = (const uint4*)(KTh + (size_t)i * MM);
    const unsigned long long* __restrict__ mbv64 = (const unsigned long long*)mbv;
    const unsigned long long* __restrict__ mbu64 = (const unsigned long long*)mbu;

    // ---- matrix rows -> registers, ONCE (8 uint4 = 32 VGPR/lane) ----
    const uint4 ku0 = MU[g0], ku1 = MU[g0 + 64], ku2 = MU[g0 + 128], ku3 = MU[g0 + 192];
    const uint4 kv0 = MV[g0], kv1 = MV[g0 + 64], kv2 = MV[g0 + 128], kv3 = MV[g0 + 192];

    // freeze history + final trackers (registers of tid<8)
    unsigned histv = 0x10000u;          // impossible 16-bit value
    float u_last = 0.0f, v_last = 0.0f;

    const unsigned long long PHMASK = 0x00007FFF00007FFFull;
    const unsigned long long FZMASK = 0x0000800000008000ull;

    for (int t = 0; t < N_ITERS; ++t) {
        // ===== u-half stage: v(t-1) -> vlds, u64 polls (2/thread) =====
        if (t == 0) {
            const unsigned long long dv =
                (unsigned long long)__half_as_ushort(__float2half(B_MARG)) *
                0x0001000100010001ULL;
            ((unsigned long long*)vlds)[tid] = dv;
        } else {
            const unsigned long long wantp =
                ((unsigned long long)((2 * t) & 0x7fff)) * 0x0000000100000001ull;
            unsigned long long g0v = ld_dev_u64(mbv64 + tid);
            unsigned long long g1v = ld_dev_u64(mbv64 + tid + 1024);
            while ((g0v & PHMASK) != wantp) {
                __builtin_amdgcn_s_sleep(1);
                g0v = ld_dev_u64(mbv64 + tid);
            }
            while ((g1v & PHMASK) != wantp) {
                __builtin_amdgcn_s_sleep(1);
                g1v = ld_dev_u64(mbv64 + tid + 1024);
            }
            ((unsigned*)vlds)[tid] =
                (unsigned)(((g0v >> 16) & 0xFFFFull) | (((g0v >> 48) & 0xFFFFull) << 16));
            ((unsigned*)vlds)[tid + 1024] =
                (unsigned)(((g1v >> 16) & 0xFFFFull) | (((g1v >> 48) & 0xFFFFull) << 16));
            const bool allf = __all(((g0v & FZMASK) == FZMASK) &&
                                    ((g1v & FZMASK) == FZMASK));
            if (lane == 0) fb_lds[w] = allf ? 1u : 0u;
        }
        __syncthreads();
        if (t != 0 && (t & 1) == 0) {
            // v(t-1)==v(t-3) bitwise everywhere -> remaining iterations
            // bit-identical; u_last/v_last already final. Exact skip.
            unsigned f = 1u;
#pragma unroll
            for (int q = 0; q < 16; ++q) f &= fb_lds[q];
            if (f) break;
        }

        // ===== u-half compute: u = a / (Kh . v), matrix from registers =====
        {
            const uint4* V = (const uint4*)vlds;
            const uint4 a = V[g0], b = V[g0 + 64], c = V[g0 + 128], d = V[g0 + 192];
            float x0 = 0.f, x1 = 0.f, x2 = 0.f, x3 = 0.f;
            x0 = dot2(ku0.x, a.x, x0); x0 = dot2(ku0.y, a.y, x0);
            x0 = dot2(ku0.z, a.z, x0); x0 = dot2(ku0.w, a.w, x0);
            x1 = dot2(ku1.x, b.x, x1); x1 = dot2(ku1.y, b.y, x1);
            x1 = dot2(ku1.z, b.z, x1); x1 = dot2(ku1.w, b.w, x1);
            x2 = dot2(ku2.x, c.x, x2); x2 = dot2(ku2.y, c.y, x2);
            x2 = dot2(ku2.z, c.z, x2); x2 = dot2(ku2.w, c.w, x2);
            x3 = dot2(ku3.x, d.x, x3); x3 = dot2(ku3.y, d.y, x3);
            x3 = dot2(ku3.z, d.z, x3); x3 = dot2(ku3.w, d.w, x3);
            float acc = (x0 + x1) + (x2 + x3);
#pragma unroll
            for (int off = 32; off > 0; off >>= 1) acc += __shfl_down(acc, off, 64);
            if (lane == 0) part[w] = acc;
        }
        __syncthreads();
        if (tid < 8) {   // publish u(t): one self-validating u32 per row
            float r = A_MARG / (part[2 * tid] + part[2 * tid + 1]);
            u_last = r;
            const unsigned val = (unsigned)__half_as_ushort(__float2half(r));
            st_dev_u32(mbu + bid * 8 + tid,
                       (val << 16) | ((unsigned)(2 * t + 1) & 0x7fffu));
        }

        // ===== v-half stage: u(t) -> vlds, u64 polls =====
        {
            const unsigned long long wantp =
                ((unsigned long long)((2 * t + 1) & 0x7fff)) * 0x0000000100000001ull;
            unsigned long long g0v = ld_dev_u64(mbu64 + tid);
            unsigned long long g1v = ld_dev_u64(mbu64 + tid + 1024);
            while ((g0v & PHMASK) != wantp) {
                __builtin_amdgcn_s_sleep(1);
                g0v = ld_dev_u64(mbu64 + tid);
            }
            while ((g1v & PHMASK) != wantp) {
                __builtin_amdgcn_s_sleep(1);
                g1v = ld_dev_u64(mbu64 + tid + 1024);
            }
            ((unsigned*)vlds)[tid] =
                (unsigned)(((g0v >> 16) & 0xFFFFull) | (((g0v >> 48) & 0xFFFFull) << 16));
            ((unsigned*)vlds)[tid + 1024] =
                (unsigned)(((g1v >> 16) & 0xFFFFull) | (((g1v >> 48) & 0xFFFFull) << 16));
        }
        __syncthreads();

        // ===== v-half compute: v = b / (KTh . u), matrix from registers =====
        {
            const uint4* V = (const uint4*)vlds;
            const uint4 a = V[g0], b = V[g0 + 64], c = V[g0 + 128], d = V[g0 + 192];
            float x0 = 0.f, x1 = 0.f, x2 = 0.f, x3 = 0.f;
            x0 = dot2(kv0.x, a.x, x0); x0 = dot2(kv0.y, a.y, x0);
            x0 = dot2(kv0.z, a.z, x0); x0 = dot2(kv0.w, a.w, x0);
            x1 = dot2(kv1.x, b.x, x1); x1 = dot2(kv1.y, b.y, x1);
            x1 = dot2(kv1.z, b.z, x1); x1 = dot2(kv1.w, b.w, x1);
            x2 = dot2(kv2.x, c.x, x2); x2 = dot2(kv2.y, c.y, x2);
            x2 = dot2(kv2.z, c.z, x2); x2 = dot2(kv2.w, c.w, x2);
            x3 = dot2(kv3.x, d.x, x3); x3 = dot2(kv3.y, d.y, x3);
            x3 = dot2(kv3.z, d.z, x3); x3 = dot2(kv3.w, d.w, x3);
            float acc = (x0 + x1) + (x2 + x3);
#pragma unroll
            for (int off = 32; off > 0; off >>= 1) acc += __shfl_down(acc, off, 64);
            if (lane == 0) part[w] = acc;
        }
        __syncthreads();
        if (tid < 8) {   // publish v(t) (+freeze bit from register hist)
            float r = B_MARG / (part[2 * tid] + part[2 * tid + 1]);
            v_last = r;
            const unsigned val = (unsigned)__half_as_ushort(__float2half(r));
            unsigned ph = (unsigned)(2 * t + 2) & 0x7fffu;
            if (t & 1) {   // v(t) vs v(t-2), register-resident history
                if (val == histv) ph |= 0x8000u;
                histv = val;
            }
            st_dev_u32(mbv + bid * 8 + tid, (val << 16) | ph);
        }
    }

    // ================== fused epilogue ==================
    // publish final fp32 v (sign bit 0 = valid; sentinel/poison have sign 1)
    if (tid < 8) {
        st_dev_u32(mbv32 + bid * 8 + tid, __float_as_uint(v_last));
        ufin[tid] = u_last;
    }
    if (tid < 8 * DD) xs[tid] = x[(size_t)(bid * 8) * DD + tid];

    // gather all 4096 final v32 (poll sign bit)
#pragma unroll
    for (int k = 0; k < 4; ++k) {
        const int idx = (k << 10) + tid;
        unsigned wv = ld_dev_u32(mbv32 + idx);
        while (wv >> 31) {
            __builtin_amdgcn_s_sleep(1);
            wv = ld_dev_u32(mbv32 + idx);
        }
        vfin[idx] = __uint_as_float(wv);
    }
    __syncthreads();

    // gamma[i][j] = u[i] * exp(-||x_i-y_j||^2/reg) * v[j]  (exact fp32 K;
    // same formula/order as the old epilogue kernel -> bit-identical)
#pragma unroll
    for (int k = 0; k < 4; ++k) {
        const int j = (k << 10) + tid;
        float yv[DD];
        const float4* y4 = (const float4*)(y + (size_t)j * DD);
#pragma unroll
        for (int q = 0; q < DD / 4; ++q) {
            float4 tq = y4[q];
            yv[4 * q + 0] = tq.x; yv[4 * q + 1] = tq.y;
            yv[4 * q + 2] = tq.z; yv[4 * q + 3] = tq.w;
        }
        const float vj = vfin[j];
#pragma unroll
        for (int r = 0; r < 8; ++r) {
            float acc = 0.0f;
#pragma unroll
            for (int q = 0; q < DD; ++q) {
                float d = xs[r * DD + q] - yv[q];
                acc = fmaf(d, d, acc);
            }
            out[(size_t)(bid * 8 + r) * MM + j] = ufin[r] * __expf(-acc * INV_REG) * vj;
        }
    }
}

extern "C" void kernel_launch(void* const* d_in, const int* in_sizes, int n_in,
                              void* d_out, int out_size, void* d_ws, size_t ws_size,
                              hipStream_t stream) {
    const float* x = (const float*)d_in[0];
    const float* y = (const float*)d_in[1];
    __half*   Kh    = (__half*)d_ws;                   // 32 MB
    __half*   KTh   = Kh + (size_t)NN * MM;            // 32 MB
    unsigned* mbu   = (unsigned*)(KTh + (size_t)NN * MM); // 16 KB u row-mailbox
    unsigned* mbv   = mbu + NN;                        // 16 KB v row-mailbox
    unsigned* mbv32 = mbv + NN;                        // 16 KB final fp32 v
    float*    out   = (float*)d_out;

    compute_K_half<<<dim3(16, 256, 2), 256, 0, stream>>>(x, y, Kh, KTh, mbu, mbv, mbv32);

    // Plain launch: 512 blocks x 16 waves = 8192 waves = device capacity;
    // co-residency by occupancy arithmetic (LDS ~26 KB x2 < 160 KB,
    // launch_bounds(1024,8) caps VGPR at 64). Proven by R15.
    sinkhorn_all<<<512, 1024, 0, stream>>>(x, y, Kh, KTh, out, mbu, mbv, mbv32);
}